// Round 2
// baseline (383.015 us; speedup 1.0000x reference)
//
#include <hip/hip_runtime.h>
#include <hip/hip_bf16.h>

#define SEQ   512
#define BATCH 256
#define ZD    64

// Broadcast lane i's value of v to all lanes (v_readlane_b32 -> SGPR operand in FMA).
__device__ __forceinline__ float lane_bcast(float v, int i) {
  return __int_as_float(__builtin_amdgcn_readlane(__float_as_int(v), i));
}

// One wave (64 lanes = 64 z-states) per chain. Chains 0..255: forward (alpha)
// for batch b = chain. Chains 256..511: backward (beta) for b = chain-256.
// Fused in one kernel so fwd and bwd run concurrently (2 waves/CU).
__global__ __launch_bounds__(64) void hmm_chains(
    const int*   __restrict__ inp,    // [SEQ, BATCH]
    const float* __restrict__ T,      // [ZD, ZD] row-major
    const float* __restrict__ pi,     // [ZD]
    const float* __restrict__ emit,   // [X, ZD]
    float* __restrict__ out_alpha,    // [SEQ, BATCH, ZD] fp32
    float* __restrict__ out_beta)     // [SEQ, BATCH, ZD] fp32
{
  const int lane  = threadIdx.x;      // z index
  const int chain = blockIdx.x;

  if (chain < BATCH) {
    // forward: alpha_t[j] = e_t[j] * sum_i alpha_{t-1}[i] * T[j][i]
    const int b = chain;
    float Trow[ZD];                   // T[lane][i], loop-invariant, lives in VGPRs
    #pragma unroll
    for (int i = 0; i < ZD; i += 4) {
      const float4 v = *reinterpret_cast<const float4*>(T + lane * ZD + i);
      Trow[i] = v.x; Trow[i+1] = v.y; Trow[i+2] = v.z; Trow[i+3] = v.w;
    }

    const int x0 = inp[b];
    float alpha = emit[x0 * ZD + lane] * pi[lane];
    out_alpha[(size_t)b * ZD + lane] = alpha;

    for (int t = 1; t < SEQ; ++t) {
      const int   xt = inp[t * BATCH + b];        // wave-uniform -> scalar load
      const float e  = emit[xt * ZD + lane];      // coalesced 256B row, issued early
      float a0 = 0.f, a1 = 0.f, a2 = 0.f, a3 = 0.f; // 4 acc chains break FMA latency
      #pragma unroll
      for (int i = 0; i < ZD; i += 4) {
        a0 = fmaf(lane_bcast(alpha, i + 0), Trow[i + 0], a0);
        a1 = fmaf(lane_bcast(alpha, i + 1), Trow[i + 1], a1);
        a2 = fmaf(lane_bcast(alpha, i + 2), Trow[i + 2], a2);
        a3 = fmaf(lane_bcast(alpha, i + 3), Trow[i + 3], a3);
      }
      alpha = e * ((a0 + a1) + (a2 + a3));
      out_alpha[((size_t)t * BATCH + b) * ZD + lane] = alpha;
    }
  } else {
    // backward: beta_t[i] = sum_j (e_{t+1}[j]*beta_{t+1}[j]) * T[j][i]
    const int b = chain - BATCH;
    float Tcol[ZD];                   // T[j][lane]
    #pragma unroll
    for (int j = 0; j < ZD; ++j) Tcol[j] = T[j * ZD + lane];

    float beta = 1.0f;
    out_beta[((size_t)(SEQ - 1) * BATCH + b) * ZD + lane] = beta;

    for (int t = SEQ - 2; t >= 0; --t) {
      const int   xt = inp[(t + 1) * BATCH + b];
      const float e  = emit[xt * ZD + lane];
      const float g  = e * beta;      // lane j holds (e_{t+1} * beta_{t+1})[j]
      float a0 = 0.f, a1 = 0.f, a2 = 0.f, a3 = 0.f;
      #pragma unroll
      for (int j = 0; j < ZD; j += 4) {
        a0 = fmaf(lane_bcast(g, j + 0), Tcol[j + 0], a0);
        a1 = fmaf(lane_bcast(g, j + 1), Tcol[j + 1], a1);
        a2 = fmaf(lane_bcast(g, j + 2), Tcol[j + 2], a2);
        a3 = fmaf(lane_bcast(g, j + 3), Tcol[j + 3], a3);
      }
      beta = (a0 + a1) + (a2 + a3);
      out_beta[((size_t)t * BATCH + b) * ZD + lane] = beta;
    }
  }
}

// posterior[t,b,z] = alpha*beta / sum_z(alpha*beta). 4 z per lane (float4),
// 16 lanes per (t,b) row, xor-shuffle reduction within the 16-lane group.
__global__ __launch_bounds__(256) void posterior_k(
    const float* __restrict__ a,
    const float* __restrict__ bt,
    float*       __restrict__ p)
{
  const int tid = blockIdx.x * 256 + threadIdx.x;
  const size_t base = (size_t)tid * 4;

  const float4 va = *reinterpret_cast<const float4*>(a  + base);
  const float4 vb = *reinterpret_cast<const float4*>(bt + base);

  const float p0 = va.x * vb.x;
  const float p1 = va.y * vb.y;
  const float p2 = va.z * vb.z;
  const float p3 = va.w * vb.w;

  float s = (p0 + p1) + (p2 + p3);
  // row = 64 z = 16 lanes; masks 1,2,4,8 stay within the 16-lane group
  s += __shfl_xor(s, 1);
  s += __shfl_xor(s, 2);
  s += __shfl_xor(s, 4);
  s += __shfl_xor(s, 8);
  const float inv = 1.0f / s;

  float4 o;
  o.x = p0 * inv;
  o.y = p1 * inv;
  o.z = p2 * inv;
  o.w = p3 * inv;
  *reinterpret_cast<float4*>(p + base) = o;
}

extern "C" void kernel_launch(void* const* d_in, const int* in_sizes, int n_in,
                              void* d_out, int out_size, void* d_ws, size_t ws_size,
                              hipStream_t stream) {
  const int*   inp  = (const int*)  d_in[0];
  const float* T    = (const float*)d_in[1];
  const float* pi   = (const float*)d_in[2];
  const float* emit = (const float*)d_in[3];

  float* out = (float*)d_out;
  const size_t N = (size_t)SEQ * BATCH * ZD;   // 8388608 per output
  float* out_alpha = out;
  float* out_beta  = out + N;
  float* out_post  = out + 2 * N;

  hipLaunchKernelGGL(hmm_chains, dim3(2 * BATCH), dim3(64), 0, stream,
                     inp, T, pi, emit, out_alpha, out_beta);

  // 256 threads * 4 elems = 1024 elems/block
  hipLaunchKernelGGL(posterior_k, dim3((unsigned)(N / 1024)), dim3(256), 0, stream,
                     out_alpha, out_beta, out_post);
}

// Round 3
// 343.889 us; speedup vs baseline: 1.1138x; 1.1138x over previous
//
#include <hip/hip_runtime.h>
#include <hip/hip_bf16.h>

#define SEQ   512
#define BATCH 256
#define ZD    64

// Broadcast lane i's value of v to all lanes (v_readlane_b32 -> SGPR operand in FMA).
__device__ __forceinline__ float lane_bcast(float v, int i) {
  return __int_as_float(__builtin_amdgcn_readlane(__float_as_int(v), i));
}

// One wave (64 lanes = 64 z-states) per chain. Chains 0..255: forward (alpha)
// for batch b = chain. Chains 256..511: backward (beta) for b = chain-256.
// Fused in one kernel so fwd and bwd run concurrently (2 waves/CU, grid-limited).
//
// __launch_bounds__(64, 1): min 1 wave/EU -> up to 512 VGPRs. Without the ",1"
// the compiler capped at 48 VGPRs and spilled the 64-register T row (round 2:
// 280us, VALUBusy 15%). T must live in VGPRs.
__global__ __launch_bounds__(64, 1) void hmm_chains(
    const int*   __restrict__ inp,    // [SEQ, BATCH]
    const float* __restrict__ T,      // [ZD, ZD] row-major
    const float* __restrict__ pi,     // [ZD]
    const float* __restrict__ emit,   // [X, ZD]
    float* __restrict__ out_alpha,    // [SEQ, BATCH, ZD] fp32
    float* __restrict__ out_beta)     // [SEQ, BATCH, ZD] fp32
{
  const int lane  = threadIdx.x;      // z index
  const int chain = blockIdx.x;

  if (chain < BATCH) {
    // forward: alpha_t[j] = e_t[j] * sum_i alpha_{t-1}[i] * T[j][i]
    const int b = chain;
    float Trow[ZD];                   // T[lane][i], loop-invariant, in VGPRs
    #pragma unroll
    for (int i = 0; i < ZD; i += 4) {
      const float4 v = *reinterpret_cast<const float4*>(T + lane * ZD + i);
      Trow[i] = v.x; Trow[i+1] = v.y; Trow[i+2] = v.z; Trow[i+3] = v.w;
    }

    const int x0 = inp[b];
    float alpha = emit[x0 * ZD + lane] * pi[lane];
    out_alpha[(size_t)b * ZD + lane] = alpha;

    // depth-2 pipeline: e_next = e for step t, x_n2 = x for step t+1
    int   x1     = inp[BATCH + b];
    float e_next = emit[x1 * ZD + lane];
    int   x_n2   = inp[2 * BATCH + b];

    for (int t = 1; t < SEQ; ++t) {
      const float e_cur = e_next;
      // prefetch: x for step t+2, e for step t+1. First use is one full
      // dot-product (~256 cyc) away -> latency hidden.
      const int   tpf  = (t + 2 < SEQ) ? (t + 2) : (SEQ - 1);
      const int   x_pf = inp[tpf * BATCH + b];
      const float e_pf = emit[x_n2 * ZD + lane];

      float a0 = 0.f, a1 = 0.f, a2 = 0.f, a3 = 0.f; // 4 acc chains break FMA latency
      #pragma unroll
      for (int i = 0; i < ZD; i += 4) {
        a0 = fmaf(lane_bcast(alpha, i + 0), Trow[i + 0], a0);
        a1 = fmaf(lane_bcast(alpha, i + 1), Trow[i + 1], a1);
        a2 = fmaf(lane_bcast(alpha, i + 2), Trow[i + 2], a2);
        a3 = fmaf(lane_bcast(alpha, i + 3), Trow[i + 3], a3);
      }
      alpha = e_cur * ((a0 + a1) + (a2 + a3));
      out_alpha[((size_t)t * BATCH + b) * ZD + lane] = alpha;

      e_next = e_pf;
      x_n2   = x_pf;
    }
  } else {
    // backward: beta_t[i] = sum_j (e_{t+1}[j]*beta_{t+1}[j]) * T[j][i]
    const int b = chain - BATCH;
    float Tcol[ZD];                   // T[j][lane]; row loads are coalesced
    #pragma unroll
    for (int j = 0; j < ZD; ++j) Tcol[j] = T[j * ZD + lane];

    float beta = 1.0f;
    out_beta[((size_t)(SEQ - 1) * BATCH + b) * ZD + lane] = beta;

    // step t consumes e_{t+1} = emit[x_{t+1}]
    int   xA     = inp[(SEQ - 1) * BATCH + b];
    float e_next = emit[xA * ZD + lane];          // for t = SEQ-2
    int   x_n2   = inp[(SEQ - 2) * BATCH + b];    // for t = SEQ-3

    for (int t = SEQ - 2; t >= 0; --t) {
      const float e_cur = e_next;
      const int   tpf  = (t - 1 > 0) ? (t - 1) : 1;  // x_{t-1} for step t-2
      const int   x_pf = inp[tpf * BATCH + b];
      const float e_pf = emit[x_n2 * ZD + lane];

      const float g = e_cur * beta;   // lane j holds (e_{t+1} * beta_{t+1})[j]
      float a0 = 0.f, a1 = 0.f, a2 = 0.f, a3 = 0.f;
      #pragma unroll
      for (int j = 0; j < ZD; j += 4) {
        a0 = fmaf(lane_bcast(g, j + 0), Tcol[j + 0], a0);
        a1 = fmaf(lane_bcast(g, j + 1), Tcol[j + 1], a1);
        a2 = fmaf(lane_bcast(g, j + 2), Tcol[j + 2], a2);
        a3 = fmaf(lane_bcast(g, j + 3), Tcol[j + 3], a3);
      }
      beta = (a0 + a1) + (a2 + a3);
      out_beta[((size_t)t * BATCH + b) * ZD + lane] = beta;

      e_next = e_pf;
      x_n2   = x_pf;
    }
  }
}

// posterior[t,b,z] = alpha*beta / sum_z(alpha*beta). 8 z per lane (2x float4),
// 8 lanes per (t,b) row, xor-shuffle reduction within the 8-lane group.
__global__ __launch_bounds__(256) void posterior_k(
    const float* __restrict__ a,
    const float* __restrict__ bt,
    float*       __restrict__ p)
{
  const int tid = blockIdx.x * 256 + threadIdx.x;
  const size_t base = (size_t)tid * 8;

  const float4 va0 = *reinterpret_cast<const float4*>(a  + base);
  const float4 va1 = *reinterpret_cast<const float4*>(a  + base + 4);
  const float4 vb0 = *reinterpret_cast<const float4*>(bt + base);
  const float4 vb1 = *reinterpret_cast<const float4*>(bt + base + 4);

  const float p0 = va0.x * vb0.x;
  const float p1 = va0.y * vb0.y;
  const float p2 = va0.z * vb0.z;
  const float p3 = va0.w * vb0.w;
  const float p4 = va1.x * vb1.x;
  const float p5 = va1.y * vb1.y;
  const float p6 = va1.z * vb1.z;
  const float p7 = va1.w * vb1.w;

  float s = ((p0 + p1) + (p2 + p3)) + ((p4 + p5) + (p6 + p7));
  // row = 64 z = 8 lanes; masks 1,2,4 stay within the aligned 8-lane group
  s += __shfl_xor(s, 1);
  s += __shfl_xor(s, 2);
  s += __shfl_xor(s, 4);
  const float inv = 1.0f / s;

  float4 o0, o1;
  o0.x = p0 * inv; o0.y = p1 * inv; o0.z = p2 * inv; o0.w = p3 * inv;
  o1.x = p4 * inv; o1.y = p5 * inv; o1.z = p6 * inv; o1.w = p7 * inv;
  *reinterpret_cast<float4*>(p + base)     = o0;
  *reinterpret_cast<float4*>(p + base + 4) = o1;
}

extern "C" void kernel_launch(void* const* d_in, const int* in_sizes, int n_in,
                              void* d_out, int out_size, void* d_ws, size_t ws_size,
                              hipStream_t stream) {
  const int*   inp  = (const int*)  d_in[0];
  const float* T    = (const float*)d_in[1];
  const float* pi   = (const float*)d_in[2];
  const float* emit = (const float*)d_in[3];

  float* out = (float*)d_out;
  const size_t N = (size_t)SEQ * BATCH * ZD;   // 8388608 per output
  float* out_alpha = out;
  float* out_beta  = out + N;
  float* out_post  = out + 2 * N;

  hipLaunchKernelGGL(hmm_chains, dim3(2 * BATCH), dim3(64), 0, stream,
                     inp, T, pi, emit, out_alpha, out_beta);

  // 256 threads * 8 elems = 2048 elems/block
  hipLaunchKernelGGL(posterior_k, dim3((unsigned)(N / 2048)), dim3(256), 0, stream,
                     out_alpha, out_beta, out_post);
}